// Round 7
// baseline (387.599 us; speedup 1.0000x reference)
//
#include <hip/hip_runtime.h>

#define B_ 2
#define S_ 2048
#define L_ 2048
#define H_ 16
#define KVH_ 4
#define D_ 128
#define HID_ 2048
#define EPS_ 1e-6f

typedef unsigned short u16;
typedef unsigned int u32;
typedef __bf16 bf16x8 __attribute__((ext_vector_type(8)));
typedef float f32x4 __attribute__((ext_vector_type(4)));
typedef unsigned u32x2v __attribute__((ext_vector_type(2)));
typedef unsigned u32x4v __attribute__((ext_vector_type(4)));

__device__ __forceinline__ float bf2f(u32 u) {
  union { u32 i; float f; } x; x.i = u << 16; return x.f;
}
__device__ __forceinline__ u16 f2bf(float f) {
  union { float f; u32 i; } x; x.f = f;
  return (u16)((x.i + 0x7fffu + ((x.i >> 16) & 1u)) >> 16);
}
__device__ __forceinline__ u32 pack_bf16(float a, float b) {
#if __has_builtin(__builtin_amdgcn_cvt_pk_bf16_f32)
  typedef __bf16 bf16x2 __attribute__((ext_vector_type(2)));
  union { bf16x2 v; u32 u; } c;
  c.v = __builtin_amdgcn_cvt_pk_bf16_f32(a, b);
  return c.u;
#else
  return (u32)f2bf(a) | ((u32)f2bf(b) << 16);
#endif
}
__device__ __forceinline__ float fexp2(float x) {
#if __has_builtin(__builtin_amdgcn_exp2f)
  return __builtin_amdgcn_exp2f(x);  // single v_exp_f32; softmax tolerates FTZ
#else
  return exp2f(x);
#endif
}
// async global->LDS, 16B per lane. LDS dest = wave-uniform base + lane*16.
__device__ __forceinline__ void gl2lds16(const u16* g, u16* l) {
  __builtin_amdgcn_global_load_lds(
      (const __attribute__((address_space(1))) u32*)g,
      (__attribute__((address_space(3))) u32*)l, 16, 0, 0);
}

#if __has_builtin(__builtin_amdgcn_permlane32_swap) && __has_builtin(__builtin_amdgcn_permlane16_swap)
#define HAS_PLS 1
#else
#define HAS_PLS 0
#endif

// MFMA C-layout (2 16x16 tiles, packed bf16 pairs) -> one K=32 A-frag.
__device__ __forceinline__ u32x4v ctoa(u32 xa, u32 xb, u32 ya, u32 yb,
                                       int quad, int l15) {
  u32x4v f;
#if HAS_PLS
  u32x2v t1 = __builtin_amdgcn_permlane32_swap(xa, ya, false, false);
  u32x2v t2 = __builtin_amdgcn_permlane16_swap(t1.x, t1.y, false, false);
  u32x2v t3 = __builtin_amdgcn_permlane32_swap(xb, yb, false, false);
  u32x2v t4 = __builtin_amdgcn_permlane16_swap(t3.x, t3.y, false, false);
  f.x = t2.x; f.y = t4.x; f.z = t2.y; f.w = t4.y;
#else
  int a0 = (((2 * quad) & 3) * 16 + l15) << 2;
  int a1 = (((2 * quad + 1) & 3) * 16 + l15) << 2;
  u32 xa0 = __builtin_amdgcn_ds_bpermute(a0, xa), ya0 = __builtin_amdgcn_ds_bpermute(a0, ya);
  u32 xb0 = __builtin_amdgcn_ds_bpermute(a0, xb), yb0 = __builtin_amdgcn_ds_bpermute(a0, yb);
  u32 xa1 = __builtin_amdgcn_ds_bpermute(a1, xa), ya1 = __builtin_amdgcn_ds_bpermute(a1, ya);
  u32 xb1 = __builtin_amdgcn_ds_bpermute(a1, xb), yb1 = __builtin_amdgcn_ds_bpermute(a1, yb);
  bool hi = quad >= 2;
  f.x = hi ? ya0 : xa0; f.y = hi ? yb0 : xb0;
  f.z = hi ? ya1 : xa1; f.w = hi ? yb1 : xb1;
#endif
  return f;
}

// ---------------- elementwise fp32 -> bf16 cast (two tensors, one launch) ----------------
__global__ __launch_bounds__(256) void cvt2_bf16(const float* __restrict__ a,
                                                 u16* __restrict__ oa,
                                                 const float* __restrict__ b,
                                                 u16* __restrict__ ob, int n4) {
  int i = blockIdx.x * 256 + threadIdx.x;
  const float* src;
  u16* dst;
  int j;
  if (i < n4) { src = a; dst = oa; j = i; }
  else { src = b; dst = ob; j = i - n4; }
  float4 v = ((const float4*)src)[j];
  uint2 o;
  o.x = pack_bf16(v.x, v.y);
  o.y = pack_bf16(v.z, v.w);
  ((uint2*)dst)[j] = o;
}

// ---------------- LDS-tiled transpose fp32[R][C] -> bf16[C][R] ----------------
__global__ __launch_bounds__(256) void transp_bf16(const float* __restrict__ A,
                                                   u16* __restrict__ At, int R, int C) {
  __shared__ float t[64][65];
  int c0 = blockIdx.x * 64, r0 = blockIdx.y * 64;
  int tx = threadIdx.x & 63, ty = threadIdx.x >> 6;
  for (int i = ty; i < 64; i += 4)
    t[i][tx] = A[(size_t)(r0 + i) * C + c0 + tx];
  __syncthreads();
  for (int i = ty; i < 64; i += 4)
    At[(size_t)(c0 + i) * R + r0 + tx] = f2bf(t[tx][i]);
}

// ---------------- bf16 GEMM: C[M][N] = A[M][K] @ Bt[N][K]^T ----------------
// 2-phase double-buffered pipeline (T3+T4): tile t+1's 8 global_load_lds per
// wave issued BEFORE computing tile t; raw `s_waitcnt vmcnt(8); s_barrier`
// keeps them in flight across the barrier (never drain to 0 in steady state).
// BK=64, XOR-swizzled LDS (slot ^= row&7 on both staged source and ds_read).
// LDS 64KB -> 2 blocks/CU.
__device__ __forceinline__ void store_out(u16* p, float v) { *p = f2bf(v); }
__device__ __forceinline__ void store_out(float* p, float v) { *p = v; }

template <typename OutT>
__device__ __forceinline__ void gemm_body(const u16* __restrict__ aP,
                                          const u16* __restrict__ bP,
                                          OutT* __restrict__ C,
                                          int m0, int n0, int N, int K,
                                          u16* sA0, u16* sA1, u16* sB0, u16* sB1) {
  const int tid = threadIdx.x;
  const int wave = tid >> 6, lane = tid & 63;
  const int quad = lane >> 4, l15 = lane & 15;
  const int wm = (wave >> 1) * 64, wn = (wave & 1) * 64;
  // staging: dest row = r0 + is*8 + lane>>3, dest 16B-slot = lane&7 (linear);
  // source slot = (lane&7) ^ ((lane>>3)&7)  => LDS[r][s] = g[r][s ^ (r&7)]
  const int sr = lane >> 3;
  const int sc = ((lane & 7) ^ ((lane >> 3) & 7)) * 8;
  const int r0 = wave * 32;
  const int sw = l15 & 7;  // read-side XOR key (row&7 == l15&7)
  u16* sA[2] = {sA0, sA1};
  u16* sB[2] = {sB0, sB1};

  f32x4 acc[4][4];
  for (int i = 0; i < 4; i++)
    for (int j = 0; j < 4; j++)
      for (int r = 0; r < 4; r++) acc[i][j][r] = 0.0f;

  auto stage = [&](int k0, int buf) {
    for (int is = 0; is < 4; is++) {
      gl2lds16(aP + (size_t)(r0 + is * 8 + sr) * K + k0 + sc, &sA[buf][(r0 + is * 8) * 64]);
      gl2lds16(bP + (size_t)(r0 + is * 8 + sr) * K + k0 + sc, &sB[buf][(r0 + is * 8) * 64]);
    }
  };

  stage(0, 0);
  int cur = 0;
  const int NT = K >> 6;
  for (int t = 0; t < NT; t++) {
    if (t + 1 < NT) {
      stage((t + 1) << 6, cur ^ 1);
      // tile t's 8 oldest loads must land; tile t+1's 8 stay in flight.
      asm volatile("s_waitcnt vmcnt(8)\n\ts_barrier" ::: "memory");
    } else {
      asm volatile("s_waitcnt vmcnt(0)\n\ts_barrier" ::: "memory");
    }
    for (int ks = 0; ks < 2; ks++) {
      bf16x8 afrag[4], bfrag[4];
      for (int i = 0; i < 4; i++)
        afrag[i] = *(const bf16x8*)&sA[cur][(wm + i * 16 + l15) * 64 + ((ks * 4 + quad) ^ sw) * 8];
      for (int j = 0; j < 4; j++)
        bfrag[j] = *(const bf16x8*)&sB[cur][(wn + j * 16 + l15) * 64 + ((ks * 4 + quad) ^ sw) * 8];
      for (int i = 0; i < 4; i++)
        for (int j = 0; j < 4; j++)
          acc[i][j] = __builtin_amdgcn_mfma_f32_16x16x32_bf16(afrag[i], bfrag[j], acc[i][j], 0, 0, 0);
    }
    // all waves done reading buf[cur] before it is restaged next iteration
    asm volatile("s_barrier" ::: "memory");
    cur ^= 1;
  }
  for (int i = 0; i < 4; i++)
    for (int j = 0; j < 4; j++) {
      int row = m0 + wm + i * 16 + quad * 4;
      int col = n0 + wn + j * 16 + l15;
      for (int r = 0; r < 4; r++)
        store_out(&C[(size_t)(row + r) * N + col], acc[i][j][r]);
    }
}

template <typename OutT>
__global__ __launch_bounds__(256, 2) void gemm_bt(const u16* __restrict__ A,
                                                  const u16* __restrict__ Bt,
                                                  OutT* __restrict__ C,
                                                  int M, int N, int K) {
  __shared__ u16 sA[2][128 * 64];
  __shared__ u16 sB[2][128 * 64];
  const int m0 = blockIdx.x * 128, n0 = blockIdx.y * 128;
  gemm_body<OutT>(A + (size_t)m0 * K, Bt + (size_t)n0 * K, C, m0, n0, N, K,
                  sA[0], sA[1], sB[0], sB[1]);
}

// Fused Q-proj + KV-proj: one 768-block launch (vs 512 + a 1-wave/SIMD 256).
__global__ __launch_bounds__(256, 2) void gemm_dual(const u16* __restrict__ A1,
                                                    const u16* __restrict__ B1,
                                                    u16* __restrict__ C1, int N1,
                                                    const u16* __restrict__ A2,
                                                    const u16* __restrict__ B2,
                                                    u16* __restrict__ C2, int N2,
                                                    int K, int ny1) {
  __shared__ u16 sA[2][128 * 64];
  __shared__ u16 sB[2][128 * 64];
  const int by = blockIdx.y;
  const u16* A; const u16* Bt; u16* C; int N, n0;
  if (by < ny1) { A = A1; Bt = B1; C = C1; N = N1; n0 = by * 128; }
  else { A = A2; Bt = B2; C = C2; N = N2; n0 = (by - ny1) * 128; }
  const int m0 = blockIdx.x * 128;
  gemm_body<u16>(A + (size_t)m0 * K, Bt + (size_t)n0 * K, C, m0, n0, N, K,
                 sA[0], sA[1], sB[0], sB[1]);
}

// ---------------- K-norm + deinterleave CKV -> K, V^T (coalesced) ----------------
__global__ __launch_bounds__(256) void knorm_deint(const u16* __restrict__ CKV,
                                                   const float* __restrict__ w,
                                                   u16* __restrict__ K,
                                                   u16* __restrict__ Vt) {
  __shared__ u16 vbuf[128][66];
  const int tid = threadIdx.x, wave = tid >> 6, lane = tid & 63;
  const int l0 = blockIdx.x * 64, kvh = blockIdx.y, b = blockIdx.z;
  for (int it = 0; it < 16; it++) {
    int ll = wave * 16 + it;
    int row = b * L_ + l0 + ll;
    const u16* src = CKV + (size_t)row * 1024 + kvh * 256;
    u32 p0 = *(const u32*)&src[lane * 2];
    u32 p1 = *(const u32*)&src[(lane + 64) * 2];
    float k0 = bf2f(p0 & 0xffff), v0 = bf2f(p0 >> 16);
    float k1 = bf2f(p1 & 0xffff), v1 = bf2f(p1 >> 16);
    float ss = k0 * k0 + k1 * k1;
    for (int off = 1; off < 64; off <<= 1) ss += __shfl_xor(ss, off);
    float sc = rsqrtf(ss * (1.0f / 128.0f) + EPS_);
    size_t kb = (((size_t)b * KVH_ + kvh) * L_ + l0 + ll) * D_;
    K[kb + lane] = f2bf(k0 * sc * w[lane]);
    K[kb + lane + 64] = f2bf(k1 * sc * w[lane + 64]);
    vbuf[lane][ll] = f2bf(v0);
    vbuf[lane + 64][ll] = f2bf(v1);
  }
  __syncthreads();
  for (int it = tid; it < 128 * 32; it += 256) {
    int d = it >> 5, cc = (it & 31) * 2;
    u32 pk = (u32)vbuf[d][cc] | ((u32)vbuf[d][cc + 1] << 16);
    *(u32*)&Vt[(((size_t)b * KVH_ + kvh) * D_ + d) * L_ + l0 + cc] = pk;
  }
}

// ---------------- flash attention (R3 structure: best measured ~87us) ----------------
// 8 waves x 16 q-rows (512-thread block): 2 blocks/CU, 4 waves/SIMD.
// KV-tile 64 double-buffered, counted-vmcnt raw barriers, XOR-swizzle, setprio.
// Runs at ~92% of the ds_read_b128 throughput ceiling (1KB LDS per MFMA).
__global__ __launch_bounds__(512, 4) void attn(const u16* __restrict__ XQ,
                                               const float* __restrict__ nw,
                                               const u16* __restrict__ K,
                                               const u16* __restrict__ Vt,
                                               u16* __restrict__ AO) {
  __shared__ u16 sk[2][4][64 * 32];   // [buf][d-chunk][l-row 64][32 d]  32KB
  __shared__ u16 sv[2][2][128 * 32];  // [buf][l-chunk][d-row 128][32 l] 32KB
  const int tid = threadIdx.x, wave = tid >> 6, lane = tid & 63;
  const int quad = lane >> 4, l15 = lane & 15;
  const int qt = blockIdx.x, h = blockIdx.y, b = blockIdx.z;
  const int kvh = h >> 2;
  const int s0 = qt * 128, wr0 = wave * 16;

  const u16* kbase = K + ((size_t)(b * KVH_ + kvh) * L_) * D_;
  const u16* vbase = Vt + ((size_t)(b * KVH_ + kvh) * D_) * L_;
  const int srow = lane >> 2;
  const int scol = ((lane & 3) ^ ((lane >> 3) & 3)) * 8;
  const int swq = (quad ^ ((l15 >> 1) & 3)) * 8;  // read-side XOR
  const int kch = wave >> 1, khalf = wave & 1;   // K: d-chunk, row-half
  const int vch = wave >> 2, vqtr = wave & 3;    // V: l-chunk, d-quarter

  auto stage = [&](int l0, int buf) {
    const u16* kb = kbase + (size_t)l0 * D_ + kch * 32;
    for (int is = 0; is < 2; is++) {
      int row = khalf * 32 + is * 16;
      gl2lds16(kb + (size_t)(row + srow) * D_ + scol, &sk[buf][kch][row * 32]);
    }
    const u16* vb = vbase + l0 + vch * 32;
    for (int is = 0; is < 2; is++) {
      int drow = vqtr * 32 + is * 16;
      gl2lds16(vb + (size_t)(drow + srow) * L_ + scol, &sv[buf][vch][drow * 32]);
    }
  };

  // ---- one-time: load 16 q-rows, fused RMSNorm (+SCALE*log2e), to A-frags ----
  bf16x8 qf[4];
  {
    const float cexp = 0.12753102331322172f;  // (1/sqrt(128)) * log2(e)
    const u16* qr = XQ + (size_t)(b * S_ + s0 + wr0 + l15) * HID_ + h * D_;
    float vals[4][8];
    float ss = 0.0f;
    for (int kc = 0; kc < 4; kc++) {
      uint4 u = *(const uint4*)&qr[kc * 32 + quad * 8];
      u32 uu[4] = {u.x, u.y, u.z, u.w};
      for (int e = 0; e < 4; e++) {
        float lo = bf2f(uu[e] & 0xffff), hi = bf2f(uu[e] >> 16);
        vals[kc][2 * e] = lo;
        vals[kc][2 * e + 1] = hi;
        ss += lo * lo + hi * hi;
      }
    }
    ss += __shfl_xor(ss, 16);
    ss += __shfl_xor(ss, 32);
    float scale = rsqrtf(ss * (1.0f / 128.0f) + EPS_) * cexp;
    for (int kc = 0; kc < 4; kc++) {
      float4 w0 = *(const float4*)&nw[kc * 32 + quad * 8];
      float4 w1 = *(const float4*)&nw[kc * 32 + quad * 8 + 4];
      union { u32x4v u; bf16x8 v; } q;
      q.u.x = pack_bf16(vals[kc][0] * scale * w0.x, vals[kc][1] * scale * w0.y);
      q.u.y = pack_bf16(vals[kc][2] * scale * w0.z, vals[kc][3] * scale * w0.w);
      q.u.z = pack_bf16(vals[kc][4] * scale * w1.x, vals[kc][5] * scale * w1.y);
      q.u.w = pack_bf16(vals[kc][6] * scale * w1.z, vals[kc][7] * scale * w1.w);
      qf[kc] = q.v;
    }
  }

  float psum = 0.0f;
  f32x4 o[8];
  for (int n = 0; n < 8; n++)
    for (int r = 0; r < 4; r++) o[n][r] = 0.0f;

  stage(0, 0);
  int cur = 0;
  const int NT = L_ / 64;  // 32
  for (int t = 0; t < NT; t++) {
    if (t + 1 < NT) {
      stage((t + 1) * 64, cur ^ 1);
      asm volatile("s_waitcnt vmcnt(4)\n\ts_barrier" ::: "memory");
    } else {
      asm volatile("s_waitcnt vmcnt(0)\n\ts_barrier" ::: "memory");
    }

    for (int cc = 0; cc < 2; cc++) {
      f32x4 sacc[2];
      for (int jj = 0; jj < 2; jj++)
        for (int r = 0; r < 4; r++) sacc[jj][r] = 0.0f;
      __builtin_amdgcn_s_setprio(1);
      for (int jj = 0; jj < 2; jj++) {
        int j = cc * 2 + jj;
        for (int kc = 0; kc < 4; kc++) {
          bf16x8 kf = *(const bf16x8*)&sk[cur][kc][(j * 16 + l15) * 32 + swq];
          sacc[jj] = __builtin_amdgcn_mfma_f32_16x16x32_bf16(kf, qf[kc], sacc[jj], 0, 0, 0);
        }
      }
      __builtin_amdgcn_s_setprio(0);
      union { u32x4v u; bf16x8 v; } pf;
      {
        float p0[4], p1[4];
        for (int r = 0; r < 4; r++) {
          p0[r] = fexp2(sacc[0][r]);
          p1[r] = fexp2(sacc[1][r]);
          psum += p0[r] + p1[r];
        }
        u32 xa = pack_bf16(p0[0], p0[1]), xb = pack_bf16(p0[2], p0[3]);
        u32 ya = pack_bf16(p1[0], p1[1]), yb = pack_bf16(p1[2], p1[3]);
        pf.u = ctoa(xa, xb, ya, yb, quad, l15);
      }
      __builtin_amdgcn_s_setprio(1);
      for (int n = 0; n < 8; n++) {
        bf16x8 vf = *(const bf16x8*)&sv[cur][cc][(n * 16 + l15) * 32 + swq];
        o[n] = __builtin_amdgcn_mfma_f32_16x16x32_bf16(pf.v, vf, o[n], 0, 0, 0);
      }
      __builtin_amdgcn_s_setprio(0);
    }
    asm volatile("s_barrier" ::: "memory");
    cur ^= 1;
  }

  // epilogue: reduce psum across quads (lane=q replicated), scale, store
  {
    float s = psum;
    s += __shfl_xor(s, 16);
    s += __shfl_xor(s, 32);
    float linv = 1.0f / s;
    float lr[4];
    for (int r = 0; r < 4; r++) lr[r] = __shfl(linv, quad * 4 + r);
    u16* ob = AO + (size_t)(b * S_ + s0 + wr0) * HID_ + h * D_;
    for (int n = 0; n < 8; n++)
      for (int r = 0; r < 4; r++)
        ob[(size_t)(quad * 4 + r) * HID_ + n * 16 + l15] = f2bf(o[n][r] * lr[r]);
  }
}

// ---------------- launch ----------------
extern "C" void kernel_launch(void* const* d_in, const int* in_sizes, int n_in,
                              void* d_out, int out_size, void* d_ws, size_t ws_size,
                              hipStream_t stream) {
  const float* x = (const float*)d_in[0];
  const float* c = (const float*)d_in[1];
  const float* wq = (const float*)d_in[2];
  const float* wkv = (const float*)d_in[3];
  const float* wo = (const float*)d_in[4];
  const float* nqw = (const float*)d_in[5];
  const float* nkw = (const float*)d_in[6];
  float* out = (float*)d_out;

  const int M = B_ * S_;  // 4096
  char* p = (char*)d_ws;
  auto alloc = [&](size_t bytes) {
    char* r = p;
    p += (bytes + 255) & ~(size_t)255;
    return r;
  };
  u16* xbf = (u16*)alloc((size_t)M * HID_ * 2);
  u16* cbf = (u16*)alloc((size_t)M * HID_ * 2);
  u16* wqT = (u16*)alloc((size_t)HID_ * HID_ * 2);
  u16* wkvT = (u16*)alloc((size_t)1024 * HID_ * 2);
  u16* woT = (u16*)alloc((size_t)HID_ * HID_ * 2);
  u16* XQ = (u16*)alloc((size_t)M * HID_ * 2);
  u16* CKV = (u16*)alloc((size_t)M * 1024 * 2);
  u16* Kb = (u16*)alloc((size_t)B_ * KVH_ * L_ * D_ * 2);
  u16* Vt = (u16*)alloc((size_t)B_ * KVH_ * D_ * L_ * 2);
  u16* AO = (u16*)alloc((size_t)M * HID_ * 2);

  const int n4 = M * HID_ / 4;
  cvt2_bf16<<<16384, 256, 0, stream>>>(x, xbf, c, cbf, n4);
  transp_bf16<<<dim3(32, 32), 256, 0, stream>>>(wq, wqT, HID_, HID_);
  transp_bf16<<<dim3(16, 32), 256, 0, stream>>>(wkv, wkvT, HID_, 1024);
  transp_bf16<<<dim3(32, 32), 256, 0, stream>>>(wo, woT, HID_, HID_);
  gemm_dual<<<dim3(32, 24), 256, 0, stream>>>(xbf, wqT, XQ, HID_,
                                              cbf, wkvT, CKV, 1024, HID_, 16);
  knorm_deint<<<dim3(32, 4, 2), 256, 0, stream>>>(CKV, nkw, Kb, Vt);
  attn<<<dim3(16, 16, 2), 512, 0, stream>>>(XQ, nqw, Kb, Vt, AO);
  gemm_bt<float><<<dim3(32, 16), 256, 0, stream>>>(AO, woT, out, M, HID_, HID_);
}

// Round 8
// 344.150 us; speedup vs baseline: 1.1263x; 1.1263x over previous
//
#include <hip/hip_runtime.h>

#define B_ 2
#define S_ 2048
#define L_ 2048
#define H_ 16
#define KVH_ 4
#define D_ 128
#define HID_ 2048
#define EPS_ 1e-6f

typedef unsigned short u16;
typedef unsigned int u32;
typedef __bf16 bf16x8 __attribute__((ext_vector_type(8)));
typedef float f32x4 __attribute__((ext_vector_type(4)));
typedef unsigned u32x2v __attribute__((ext_vector_type(2)));
typedef unsigned u32x4v __attribute__((ext_vector_type(4)));

__device__ __forceinline__ float bf2f(u32 u) {
  union { u32 i; float f; } x; x.i = u << 16; return x.f;
}
__device__ __forceinline__ u16 f2bf(float f) {
  union { float f; u32 i; } x; x.f = f;
  return (u16)((x.i + 0x7fffu + ((x.i >> 16) & 1u)) >> 16);
}
__device__ __forceinline__ u32 pack_bf16(float a, float b) {
#if __has_builtin(__builtin_amdgcn_cvt_pk_bf16_f32)
  typedef __bf16 bf16x2 __attribute__((ext_vector_type(2)));
  union { bf16x2 v; u32 u; } c;
  c.v = __builtin_amdgcn_cvt_pk_bf16_f32(a, b);
  return c.u;
#else
  return (u32)f2bf(a) | ((u32)f2bf(b) << 16);
#endif
}
__device__ __forceinline__ float fexp2(float x) {
#if __has_builtin(__builtin_amdgcn_exp2f)
  return __builtin_amdgcn_exp2f(x);  // single v_exp_f32; softmax tolerates FTZ
#else
  return exp2f(x);
#endif
}
// async global->LDS, 16B per lane. LDS dest = wave-uniform base + lane*16.
__device__ __forceinline__ void gl2lds16(const u16* g, u16* l) {
  __builtin_amdgcn_global_load_lds(
      (const __attribute__((address_space(1))) u32*)g,
      (__attribute__((address_space(3))) u32*)l, 16, 0, 0);
}

#if __has_builtin(__builtin_amdgcn_permlane32_swap) && __has_builtin(__builtin_amdgcn_permlane16_swap)
#define HAS_PLS 1
#else
#define HAS_PLS 0
#endif

// MFMA C-layout (2 16x16 tiles, packed bf16 pairs) -> one K=32 A-frag.
__device__ __forceinline__ u32x4v ctoa(u32 xa, u32 xb, u32 ya, u32 yb,
                                       int quad, int l15) {
  u32x4v f;
#if HAS_PLS
  u32x2v t1 = __builtin_amdgcn_permlane32_swap(xa, ya, false, false);
  u32x2v t2 = __builtin_amdgcn_permlane16_swap(t1.x, t1.y, false, false);
  u32x2v t3 = __builtin_amdgcn_permlane32_swap(xb, yb, false, false);
  u32x2v t4 = __builtin_amdgcn_permlane16_swap(t3.x, t3.y, false, false);
  f.x = t2.x; f.y = t4.x; f.z = t2.y; f.w = t4.y;
#else
  int a0 = (((2 * quad) & 3) * 16 + l15) << 2;
  int a1 = (((2 * quad + 1) & 3) * 16 + l15) << 2;
  u32 xa0 = __builtin_amdgcn_ds_bpermute(a0, xa), ya0 = __builtin_amdgcn_ds_bpermute(a0, ya);
  u32 xb0 = __builtin_amdgcn_ds_bpermute(a0, xb), yb0 = __builtin_amdgcn_ds_bpermute(a0, yb);
  u32 xa1 = __builtin_amdgcn_ds_bpermute(a1, xa), ya1 = __builtin_amdgcn_ds_bpermute(a1, ya);
  u32 xb1 = __builtin_amdgcn_ds_bpermute(a1, xb), yb1 = __builtin_amdgcn_ds_bpermute(a1, yb);
  bool hi = quad >= 2;
  f.x = hi ? ya0 : xa0; f.y = hi ? yb0 : xb0;
  f.z = hi ? ya1 : xa1; f.w = hi ? yb1 : xb1;
#endif
  return f;
}

// ---------------- elementwise fp32 -> bf16 cast (two tensors, one launch) ----------------
__global__ __launch_bounds__(256) void cvt2_bf16(const float* __restrict__ a,
                                                 u16* __restrict__ oa,
                                                 const float* __restrict__ b,
                                                 u16* __restrict__ ob, int n4) {
  int i = blockIdx.x * 256 + threadIdx.x;
  const float* src;
  u16* dst;
  int j;
  if (i < n4) { src = a; dst = oa; j = i; }
  else { src = b; dst = ob; j = i - n4; }
  float4 v = ((const float4*)src)[j];
  uint2 o;
  o.x = pack_bf16(v.x, v.y);
  o.y = pack_bf16(v.z, v.w);
  ((uint2*)dst)[j] = o;
}

// ---------------- LDS-tiled transpose fp32[R][C] -> bf16[C][R] ----------------
__global__ __launch_bounds__(256) void transp_bf16(const float* __restrict__ A,
                                                   u16* __restrict__ At, int R, int C) {
  __shared__ float t[64][65];
  int c0 = blockIdx.x * 64, r0 = blockIdx.y * 64;
  int tx = threadIdx.x & 63, ty = threadIdx.x >> 6;
  for (int i = ty; i < 64; i += 4)
    t[i][tx] = A[(size_t)(r0 + i) * C + c0 + tx];
  __syncthreads();
  for (int i = ty; i < 64; i += 4)
    At[(size_t)(c0 + i) * R + r0 + tx] = f2bf(t[tx][i]);
}

// ---------------- bf16 GEMM: C[M][N] = A[M][K] @ Bt[N][K]^T ----------------
// 1-phase, BK=64, 32KB LDS -> 5 blocks/CU (20 waves/CU): cross-block TLP
// hides the staging drain (m114). R7 lesson: buying a 2-phase pipeline with
// 64KB dbuf halves occupancy and NETS NEGATIVE at this grid -- never trade
// occupancy for explicit pipelining. XOR-swizzle: slot ^= row&7 on both the
// staged global source and the ds_read (16-way conflict -> 2-way, free).
__device__ __forceinline__ void store_out(u16* p, float v) { *p = f2bf(v); }
__device__ __forceinline__ void store_out(float* p, float v) { *p = v; }

template <typename OutT>
__device__ __forceinline__ void gemm_body(const u16* __restrict__ aP,
                                          const u16* __restrict__ bP,
                                          OutT* __restrict__ C,
                                          int m0, int n0, int N, int K,
                                          u16* sA, u16* sB) {
  const int tid = threadIdx.x;
  const int wave = tid >> 6, lane = tid & 63;
  const int quad = lane >> 4, l15 = lane & 15;
  const int wm = (wave >> 1) * 64, wn = (wave & 1) * 64;
  // staging: dest row = r0 + is*8 + lane>>3, dest 16B-slot = lane&7 (linear);
  // source slot = (lane&7) ^ ((lane>>3)&7)  => LDS[r][s] = g[r][s ^ (r&7)]
  const int sr = lane >> 3;
  const int sc = ((lane & 7) ^ ((lane >> 3) & 7)) * 8;
  const int r0 = wave * 32;
  const int sw = l15 & 7;  // read-side XOR key (row&7 == l15&7)

  f32x4 acc[4][4];
  for (int i = 0; i < 4; i++)
    for (int j = 0; j < 4; j++)
      for (int r = 0; r < 4; r++) acc[i][j][r] = 0.0f;

  for (int k0 = 0; k0 < K; k0 += 64) {
    for (int is = 0; is < 4; is++) {
      gl2lds16(aP + (size_t)(r0 + is * 8 + sr) * K + k0 + sc, &sA[(r0 + is * 8) * 64]);
      gl2lds16(bP + (size_t)(r0 + is * 8 + sr) * K + k0 + sc, &sB[(r0 + is * 8) * 64]);
    }
    __syncthreads();
    for (int ks = 0; ks < 2; ks++) {
      bf16x8 afrag[4], bfrag[4];
      for (int i = 0; i < 4; i++)
        afrag[i] = *(const bf16x8*)&sA[(wm + i * 16 + l15) * 64 + ((ks * 4 + quad) ^ sw) * 8];
      for (int j = 0; j < 4; j++)
        bfrag[j] = *(const bf16x8*)&sB[(wn + j * 16 + l15) * 64 + ((ks * 4 + quad) ^ sw) * 8];
      for (int i = 0; i < 4; i++)
        for (int j = 0; j < 4; j++)
          acc[i][j] = __builtin_amdgcn_mfma_f32_16x16x32_bf16(afrag[i], bfrag[j], acc[i][j], 0, 0, 0);
    }
    __syncthreads();
  }
  for (int i = 0; i < 4; i++)
    for (int j = 0; j < 4; j++) {
      int row = m0 + wm + i * 16 + quad * 4;
      int col = n0 + wn + j * 16 + l15;
      for (int r = 0; r < 4; r++)
        store_out(&C[(size_t)(row + r) * N + col], acc[i][j][r]);
    }
}

template <typename OutT>
__global__ __launch_bounds__(256, 2) void gemm_bt(const u16* __restrict__ A,
                                                  const u16* __restrict__ Bt,
                                                  OutT* __restrict__ C,
                                                  int M, int N, int K) {
  __shared__ u16 sA[128 * 64];
  __shared__ u16 sB[128 * 64];
  const int m0 = blockIdx.x * 128, n0 = blockIdx.y * 128;
  gemm_body<OutT>(A + (size_t)m0 * K, Bt + (size_t)n0 * K, C, m0, n0, N, K, sA, sB);
}

// Fused Q-proj + KV-proj: one 768-block launch (vs 512 + a 1-wave/SIMD 256).
__global__ __launch_bounds__(256, 2) void gemm_dual(const u16* __restrict__ A1,
                                                    const u16* __restrict__ B1,
                                                    u16* __restrict__ C1, int N1,
                                                    const u16* __restrict__ A2,
                                                    const u16* __restrict__ B2,
                                                    u16* __restrict__ C2, int N2,
                                                    int K, int ny1) {
  __shared__ u16 sA[128 * 64];
  __shared__ u16 sB[128 * 64];
  const int by = blockIdx.y;
  const u16* A; const u16* Bt; u16* C; int N, n0;
  if (by < ny1) { A = A1; Bt = B1; C = C1; N = N1; n0 = by * 128; }
  else { A = A2; Bt = B2; C = C2; N = N2; n0 = (by - ny1) * 128; }
  const int m0 = blockIdx.x * 128;
  gemm_body<u16>(A + (size_t)m0 * K, Bt + (size_t)n0 * K, C, m0, n0, N, K, sA, sB);
}

// ---------------- K-norm + deinterleave CKV -> K, V^T (coalesced) ----------------
__global__ __launch_bounds__(256) void knorm_deint(const u16* __restrict__ CKV,
                                                   const float* __restrict__ w,
                                                   u16* __restrict__ K,
                                                   u16* __restrict__ Vt) {
  __shared__ u16 vbuf[128][66];
  const int tid = threadIdx.x, wave = tid >> 6, lane = tid & 63;
  const int l0 = blockIdx.x * 64, kvh = blockIdx.y, b = blockIdx.z;
  for (int it = 0; it < 16; it++) {
    int ll = wave * 16 + it;
    int row = b * L_ + l0 + ll;
    const u16* src = CKV + (size_t)row * 1024 + kvh * 256;
    u32 p0 = *(const u32*)&src[lane * 2];
    u32 p1 = *(const u32*)&src[(lane + 64) * 2];
    float k0 = bf2f(p0 & 0xffff), v0 = bf2f(p0 >> 16);
    float k1 = bf2f(p1 & 0xffff), v1 = bf2f(p1 >> 16);
    float ss = k0 * k0 + k1 * k1;
    for (int off = 1; off < 64; off <<= 1) ss += __shfl_xor(ss, off);
    float sc = rsqrtf(ss * (1.0f / 128.0f) + EPS_);
    size_t kb = (((size_t)b * KVH_ + kvh) * L_ + l0 + ll) * D_;
    K[kb + lane] = f2bf(k0 * sc * w[lane]);
    K[kb + lane + 64] = f2bf(k1 * sc * w[lane + 64]);
    vbuf[lane][ll] = f2bf(v0);
    vbuf[lane + 64][ll] = f2bf(v1);
  }
  __syncthreads();
  for (int it = tid; it < 128 * 32; it += 256) {
    int d = it >> 5, cc = (it & 31) * 2;
    u32 pk = (u32)vbuf[d][cc] | ((u32)vbuf[d][cc + 1] << 16);
    *(u32*)&Vt[(((size_t)b * KVH_ + kvh) * D_ + d) * L_ + l0 + cc] = pk;
  }
}

// ---------------- flash attention (R3 structure: best measured ~87us) ----------------
// 8 waves x 16 q-rows (512-thread block): 2 blocks/CU, 4 waves/SIMD.
// KV-tile 64 double-buffered, counted-vmcnt raw barriers, XOR-swizzle, setprio.
// Runs at ~92% of the ds_read_b128 throughput ceiling (1KB LDS per MFMA).
// (Here the grid pins occupancy at 2 blocks/CU regardless, so the 2-phase
// pipeline is pure gain -- unlike the GEMM, where it cost occupancy.)
__global__ __launch_bounds__(512, 4) void attn(const u16* __restrict__ XQ,
                                               const float* __restrict__ nw,
                                               const u16* __restrict__ K,
                                               const u16* __restrict__ Vt,
                                               u16* __restrict__ AO) {
  __shared__ u16 sk[2][4][64 * 32];   // [buf][d-chunk][l-row 64][32 d]  32KB
  __shared__ u16 sv[2][2][128 * 32];  // [buf][l-chunk][d-row 128][32 l] 32KB
  const int tid = threadIdx.x, wave = tid >> 6, lane = tid & 63;
  const int quad = lane >> 4, l15 = lane & 15;
  const int qt = blockIdx.x, h = blockIdx.y, b = blockIdx.z;
  const int kvh = h >> 2;
  const int s0 = qt * 128, wr0 = wave * 16;

  const u16* kbase = K + ((size_t)(b * KVH_ + kvh) * L_) * D_;
  const u16* vbase = Vt + ((size_t)(b * KVH_ + kvh) * D_) * L_;
  const int srow = lane >> 2;
  const int scol = ((lane & 3) ^ ((lane >> 3) & 3)) * 8;
  const int swq = (quad ^ ((l15 >> 1) & 3)) * 8;  // read-side XOR
  const int kch = wave >> 1, khalf = wave & 1;   // K: d-chunk, row-half
  const int vch = wave >> 2, vqtr = wave & 3;    // V: l-chunk, d-quarter

  auto stage = [&](int l0, int buf) {
    const u16* kb = kbase + (size_t)l0 * D_ + kch * 32;
    for (int is = 0; is < 2; is++) {
      int row = khalf * 32 + is * 16;
      gl2lds16(kb + (size_t)(row + srow) * D_ + scol, &sk[buf][kch][row * 32]);
    }
    const u16* vb = vbase + l0 + vch * 32;
    for (int is = 0; is < 2; is++) {
      int drow = vqtr * 32 + is * 16;
      gl2lds16(vb + (size_t)(drow + srow) * L_ + scol, &sv[buf][vch][drow * 32]);
    }
  };

  // ---- one-time: load 16 q-rows, fused RMSNorm (+SCALE*log2e), to A-frags ----
  bf16x8 qf[4];
  {
    const float cexp = 0.12753102331322172f;  // (1/sqrt(128)) * log2(e)
    const u16* qr = XQ + (size_t)(b * S_ + s0 + wr0 + l15) * HID_ + h * D_;
    float vals[4][8];
    float ss = 0.0f;
    for (int kc = 0; kc < 4; kc++) {
      uint4 u = *(const uint4*)&qr[kc * 32 + quad * 8];
      u32 uu[4] = {u.x, u.y, u.z, u.w};
      for (int e = 0; e < 4; e++) {
        float lo = bf2f(uu[e] & 0xffff), hi = bf2f(uu[e] >> 16);
        vals[kc][2 * e] = lo;
        vals[kc][2 * e + 1] = hi;
        ss += lo * lo + hi * hi;
      }
    }
    ss += __shfl_xor(ss, 16);
    ss += __shfl_xor(ss, 32);
    float scale = rsqrtf(ss * (1.0f / 128.0f) + EPS_) * cexp;
    for (int kc = 0; kc < 4; kc++) {
      float4 w0 = *(const float4*)&nw[kc * 32 + quad * 8];
      float4 w1 = *(const float4*)&nw[kc * 32 + quad * 8 + 4];
      union { u32x4v u; bf16x8 v; } q;
      q.u.x = pack_bf16(vals[kc][0] * scale * w0.x, vals[kc][1] * scale * w0.y);
      q.u.y = pack_bf16(vals[kc][2] * scale * w0.z, vals[kc][3] * scale * w0.w);
      q.u.z = pack_bf16(vals[kc][4] * scale * w1.x, vals[kc][5] * scale * w1.y);
      q.u.w = pack_bf16(vals[kc][6] * scale * w1.z, vals[kc][7] * scale * w1.w);
      qf[kc] = q.v;
    }
  }

  float psum = 0.0f;
  f32x4 o[8];
  for (int n = 0; n < 8; n++)
    for (int r = 0; r < 4; r++) o[n][r] = 0.0f;

  stage(0, 0);
  int cur = 0;
  const int NT = L_ / 64;  // 32
  for (int t = 0; t < NT; t++) {
    if (t + 1 < NT) {
      stage((t + 1) * 64, cur ^ 1);
      asm volatile("s_waitcnt vmcnt(4)\n\ts_barrier" ::: "memory");
    } else {
      asm volatile("s_waitcnt vmcnt(0)\n\ts_barrier" ::: "memory");
    }

    for (int cc = 0; cc < 2; cc++) {
      f32x4 sacc[2];
      for (int jj = 0; jj < 2; jj++)
        for (int r = 0; r < 4; r++) sacc[jj][r] = 0.0f;
      __builtin_amdgcn_s_setprio(1);
      for (int jj = 0; jj < 2; jj++) {
        int j = cc * 2 + jj;
        for (int kc = 0; kc < 4; kc++) {
          bf16x8 kf = *(const bf16x8*)&sk[cur][kc][(j * 16 + l15) * 32 + swq];
          sacc[jj] = __builtin_amdgcn_mfma_f32_16x16x32_bf16(kf, qf[kc], sacc[jj], 0, 0, 0);
        }
      }
      __builtin_amdgcn_s_setprio(0);
      union { u32x4v u; bf16x8 v; } pf;
      {
        float p0[4], p1[4];
        for (int r = 0; r < 4; r++) {
          p0[r] = fexp2(sacc[0][r]);
          p1[r] = fexp2(sacc[1][r]);
          psum += p0[r] + p1[r];
        }
        u32 xa = pack_bf16(p0[0], p0[1]), xb = pack_bf16(p0[2], p0[3]);
        u32 ya = pack_bf16(p1[0], p1[1]), yb = pack_bf16(p1[2], p1[3]);
        pf.u = ctoa(xa, xb, ya, yb, quad, l15);
      }
      __builtin_amdgcn_s_setprio(1);
      for (int n = 0; n < 8; n++) {
        bf16x8 vf = *(const bf16x8*)&sv[cur][cc][(n * 16 + l15) * 32 + swq];
        o[n] = __builtin_amdgcn_mfma_f32_16x16x32_bf16(pf.v, vf, o[n], 0, 0, 0);
      }
      __builtin_amdgcn_s_setprio(0);
    }
    asm volatile("s_barrier" ::: "memory");
    cur ^= 1;
  }

  // epilogue: reduce psum across quads (lane=q replicated), scale, store
  {
    float s = psum;
    s += __shfl_xor(s, 16);
    s += __shfl_xor(s, 32);
    float linv = 1.0f / s;
    float lr[4];
    for (int r = 0; r < 4; r++) lr[r] = __shfl(linv, quad * 4 + r);
    u16* ob = AO + (size_t)(b * S_ + s0 + wr0) * HID_ + h * D_;
    for (int n = 0; n < 8; n++)
      for (int r = 0; r < 4; r++)
        ob[(size_t)(quad * 4 + r) * HID_ + n * 16 + l15] = f2bf(o[n][r] * lr[r]);
  }
}

// ---------------- launch ----------------
extern "C" void kernel_launch(void* const* d_in, const int* in_sizes, int n_in,
                              void* d_out, int out_size, void* d_ws, size_t ws_size,
                              hipStream_t stream) {
  const float* x = (const float*)d_in[0];
  const float* c = (const float*)d_in[1];
  const float* wq = (const float*)d_in[2];
  const float* wkv = (const float*)d_in[3];
  const float* wo = (const float*)d_in[4];
  const float* nqw = (const float*)d_in[5];
  const float* nkw = (const float*)d_in[6];
  float* out = (float*)d_out;

  const int M = B_ * S_;  // 4096
  char* p = (char*)d_ws;
  auto alloc = [&](size_t bytes) {
    char* r = p;
    p += (bytes + 255) & ~(size_t)255;
    return r;
  };
  u16* xbf = (u16*)alloc((size_t)M * HID_ * 2);
  u16* cbf = (u16*)alloc((size_t)M * HID_ * 2);
  u16* wqT = (u16*)alloc((size_t)HID_ * HID_ * 2);
  u16* wkvT = (u16*)alloc((size_t)1024 * HID_ * 2);
  u16* woT = (u16*)alloc((size_t)HID_ * HID_ * 2);
  u16* XQ = (u16*)alloc((size_t)M * HID_ * 2);
  u16* CKV = (u16*)alloc((size_t)M * 1024 * 2);
  u16* Kb = (u16*)alloc((size_t)B_ * KVH_ * L_ * D_ * 2);
  u16* Vt = (u16*)alloc((size_t)B_ * KVH_ * D_ * L_ * 2);
  u16* AO = (u16*)alloc((size_t)M * HID_ * 2);

  const int n4 = M * HID_ / 4;
  cvt2_bf16<<<16384, 256, 0, stream>>>(x, xbf, c, cbf, n4);
  transp_bf16<<<dim3(32, 32), 256, 0, stream>>>(wq, wqT, HID_, HID_);
  transp_bf16<<<dim3(16, 32), 256, 0, stream>>>(wkv, wkvT, HID_, 1024);
  transp_bf16<<<dim3(32, 32), 256, 0, stream>>>(wo, woT, HID_, HID_);
  gemm_dual<<<dim3(32, 24), 256, 0, stream>>>(xbf, wqT, XQ, HID_,
                                              cbf, wkvT, CKV, 1024, HID_, 16);
  knorm_deint<<<dim3(32, 4, 2), 256, 0, stream>>>(CKV, nkw, Kb, Vt);
  attn<<<dim3(16, 16, 2), 512, 0, stream>>>(XQ, nqw, Kb, Vt, AO);
  gemm_bt<float><<<dim3(32, 16), 256, 0, stream>>>(AO, woT, out, M, HID_, HID_);
}

// Round 9
// 337.150 us; speedup vs baseline: 1.1496x; 1.0208x over previous
//
#include <hip/hip_runtime.h>

#define B_ 2
#define S_ 2048
#define L_ 2048
#define H_ 16
#define KVH_ 4
#define D_ 128
#define HID_ 2048
#define EPS_ 1e-6f

typedef unsigned short u16;
typedef unsigned int u32;
typedef __bf16 bf16x8 __attribute__((ext_vector_type(8)));
typedef float f32x4 __attribute__((ext_vector_type(4)));
typedef unsigned u32x2v __attribute__((ext_vector_type(2)));
typedef unsigned u32x4v __attribute__((ext_vector_type(4)));

__device__ __forceinline__ float bf2f(u32 u) {
  union { u32 i; float f; } x; x.i = u << 16; return x.f;
}
__device__ __forceinline__ u16 f2bf(float f) {
  union { float f; u32 i; } x; x.f = f;
  return (u16)((x.i + 0x7fffu + ((x.i >> 16) & 1u)) >> 16);
}
__device__ __forceinline__ u32 pack_bf16(float a, float b) {
#if __has_builtin(__builtin_amdgcn_cvt_pk_bf16_f32)
  typedef __bf16 bf16x2 __attribute__((ext_vector_type(2)));
  union { bf16x2 v; u32 u; } c;
  c.v = __builtin_amdgcn_cvt_pk_bf16_f32(a, b);
  return c.u;
#else
  return (u32)f2bf(a) | ((u32)f2bf(b) << 16);
#endif
}
__device__ __forceinline__ float fexp2(float x) {
#if __has_builtin(__builtin_amdgcn_exp2f)
  return __builtin_amdgcn_exp2f(x);  // single v_exp_f32; softmax tolerates FTZ
#else
  return exp2f(x);
#endif
}
// async global->LDS, 16B per lane. LDS dest = wave-uniform base + lane*16.
__device__ __forceinline__ void gl2lds16(const u16* g, u16* l) {
  __builtin_amdgcn_global_load_lds(
      (const __attribute__((address_space(1))) u32*)g,
      (__attribute__((address_space(3))) u32*)l, 16, 0, 0);
}

#if __has_builtin(__builtin_amdgcn_permlane32_swap) && __has_builtin(__builtin_amdgcn_permlane16_swap)
#define HAS_PLS 1
#else
#define HAS_PLS 0
#endif

// MFMA C-layout (2 16x16 tiles, packed bf16 pairs) -> one K=32 A-frag.
__device__ __forceinline__ u32x4v ctoa(u32 xa, u32 xb, u32 ya, u32 yb,
                                       int quad, int l15) {
  u32x4v f;
#if HAS_PLS
  u32x2v t1 = __builtin_amdgcn_permlane32_swap(xa, ya, false, false);
  u32x2v t2 = __builtin_amdgcn_permlane16_swap(t1.x, t1.y, false, false);
  u32x2v t3 = __builtin_amdgcn_permlane32_swap(xb, yb, false, false);
  u32x2v t4 = __builtin_amdgcn_permlane16_swap(t3.x, t3.y, false, false);
  f.x = t2.x; f.y = t4.x; f.z = t2.y; f.w = t4.y;
#else
  int a0 = (((2 * quad) & 3) * 16 + l15) << 2;
  int a1 = (((2 * quad + 1) & 3) * 16 + l15) << 2;
  u32 xa0 = __builtin_amdgcn_ds_bpermute(a0, xa), ya0 = __builtin_amdgcn_ds_bpermute(a0, ya);
  u32 xb0 = __builtin_amdgcn_ds_bpermute(a0, xb), yb0 = __builtin_amdgcn_ds_bpermute(a0, yb);
  u32 xa1 = __builtin_amdgcn_ds_bpermute(a1, xa), ya1 = __builtin_amdgcn_ds_bpermute(a1, ya);
  u32 xb1 = __builtin_amdgcn_ds_bpermute(a1, xb), yb1 = __builtin_amdgcn_ds_bpermute(a1, yb);
  bool hi = quad >= 2;
  f.x = hi ? ya0 : xa0; f.y = hi ? yb0 : xb0;
  f.z = hi ? ya1 : xa1; f.w = hi ? yb1 : xb1;
#endif
  return f;
}

// ---------------- fused prep: cvt(x), cvt(c), transp(wq), transp(wkv), transp(wo) ----------------
// One launch instead of four. Blocks [0,16384): bf16 casts; then 1024 wq,
// 512 wkv, 1024 wo transpose tiles.
__global__ __launch_bounds__(256) void prep(const float* __restrict__ x, u16* __restrict__ xbf,
                                            const float* __restrict__ c, u16* __restrict__ cbf,
                                            const float* __restrict__ wq, u16* __restrict__ wqT,
                                            const float* __restrict__ wkv, u16* __restrict__ wkvT,
                                            const float* __restrict__ wo, u16* __restrict__ woT,
                                            int n4) {
  __shared__ float t[64][65];
  int bid = blockIdx.x;
  if (bid < 16384) {
    int i = bid * 256 + threadIdx.x;
    const float* src; u16* dst; int j;
    if (i < n4) { src = x; dst = xbf; j = i; }
    else { src = c; dst = cbf; j = i - n4; }
    float4 v = ((const float4*)src)[j];
    uint2 o;
    o.x = pack_bf16(v.x, v.y);
    o.y = pack_bf16(v.z, v.w);
    ((uint2*)dst)[j] = o;
    return;
  }
  int id = bid - 16384;
  const float* A; u16* At; int R, C, cb, rb;
  if (id < 1024) { A = wq; At = wqT; R = 2048; C = 2048; cb = id & 31; rb = id >> 5; }
  else if (id < 1536) { id -= 1024; A = wkv; At = wkvT; R = 2048; C = 1024; cb = id & 15; rb = id >> 4; }
  else { id -= 1536; A = wo; At = woT; R = 2048; C = 2048; cb = id & 31; rb = id >> 5; }
  int c0 = cb * 64, r0 = rb * 64;
  int tx = threadIdx.x & 63, ty = threadIdx.x >> 6;
  for (int i = ty; i < 64; i += 4)
    t[i][tx] = A[(size_t)(r0 + i) * C + c0 + tx];
  __syncthreads();
  for (int i = ty; i < 64; i += 4)
    At[(size_t)(c0 + i) * R + r0 + tx] = f2bf(t[tx][i]);
}

// ---------------- bf16 GEMM body: C[M][N] = A[M][K] @ Bt[N][K]^T ----------------
// 1-phase, BK=64, 32KB LDS -> 5 blocks/CU capacity: cross-block TLP hides the
// staging drain (m114). R7 lesson: 2-phase dbuf at 64KB halves occupancy and
// nets negative -- never trade occupancy for explicit pipelining here.
// XOR-swizzle: slot ^= row&7 on both the staged global source and the ds_read.
template <typename OutT>
__device__ __forceinline__ void gemm_body(const u16* __restrict__ aP,
                                          const u16* __restrict__ bP,
                                          OutT* __restrict__ C,
                                          int m0, int n0, int N, int K,
                                          u16* sA, u16* sB) {
  const int tid = threadIdx.x;
  const int wave = tid >> 6, lane = tid & 63;
  const int quad = lane >> 4, l15 = lane & 15;
  const int wm = (wave >> 1) * 64, wn = (wave & 1) * 64;
  const int sr = lane >> 3;
  const int sc = ((lane & 7) ^ ((lane >> 3) & 7)) * 8;
  const int r0 = wave * 32;
  const int sw = l15 & 7;  // read-side XOR key (row&7 == l15&7)

  f32x4 acc[4][4];
  for (int i = 0; i < 4; i++)
    for (int j = 0; j < 4; j++)
      for (int r = 0; r < 4; r++) acc[i][j][r] = 0.0f;

  for (int k0 = 0; k0 < K; k0 += 64) {
    for (int is = 0; is < 4; is++) {
      gl2lds16(aP + (size_t)(r0 + is * 8 + sr) * K + k0 + sc, &sA[(r0 + is * 8) * 64]);
      gl2lds16(bP + (size_t)(r0 + is * 8 + sr) * K + k0 + sc, &sB[(r0 + is * 8) * 64]);
    }
    __syncthreads();
    for (int ks = 0; ks < 2; ks++) {
      bf16x8 afrag[4], bfrag[4];
      for (int i = 0; i < 4; i++)
        afrag[i] = *(const bf16x8*)&sA[(wm + i * 16 + l15) * 64 + ((ks * 4 + quad) ^ sw) * 8];
      for (int j = 0; j < 4; j++)
        bfrag[j] = *(const bf16x8*)&sB[(wn + j * 16 + l15) * 64 + ((ks * 4 + quad) ^ sw) * 8];
      for (int i = 0; i < 4; i++)
        for (int j = 0; j < 4; j++)
          acc[i][j] = __builtin_amdgcn_mfma_f32_16x16x32_bf16(afrag[i], bfrag[j], acc[i][j], 0, 0, 0);
    }
    __syncthreads();
  }
  for (int i = 0; i < 4; i++)
    for (int j = 0; j < 4; j++) {
      int row = m0 + wm + i * 16 + quad * 4;
      int col = n0 + wn + j * 16 + l15;
      for (int r = 0; r < 4; r++) {
        float v = acc[i][j][r];
        OutT* p = &C[(size_t)(row + r) * N + col];
        if constexpr (sizeof(OutT) == 2) *p = (OutT)f2bf(v); else *p = (OutT)v;
      }
    }
}

// Fused Q-proj + KV-proj: one 768-block launch (3 blocks/CU).
__global__ __launch_bounds__(256, 2) void gemm_dual(const u16* __restrict__ A1,
                                                    const u16* __restrict__ B1,
                                                    u16* __restrict__ C1, int N1,
                                                    const u16* __restrict__ A2,
                                                    const u16* __restrict__ B2,
                                                    u16* __restrict__ C2, int N2,
                                                    int K, int ny1) {
  __shared__ u16 sA[128 * 64];
  __shared__ u16 sB[128 * 64];
  const int by = blockIdx.y;
  const u16* A; const u16* Bt; u16* C; int N, n0;
  if (by < ny1) { A = A1; Bt = B1; C = C1; N = N1; n0 = by * 128; }
  else { A = A2; Bt = B2; C = C2; N = N2; n0 = (by - ny1) * 128; }
  const int m0 = blockIdx.x * 128;
  gemm_body<u16>(A + (size_t)m0 * K, Bt + (size_t)n0 * K, C, m0, n0, N, K, sA, sB);
}

// ---------------- out-GEMM: 128m x 64n tiles -> 1024 blocks = 4 blocks/CU ----------------
// The 128x128 grid (512 blocks) was grid-limited to 2 blocks/CU = 8 waves/CU:
// too few waves to hide the 1-phase staging drain. 64n doubles the grid and
// resident waves (16/CU, LDS 24KB) at +50% B-side staging traffic -- BW has
// ample headroom (~1 of 6.3 TB/s). Each wave owns 32m x 64n (acc[2][4]).
__global__ __launch_bounds__(256, 2) void gemm_out64(const u16* __restrict__ A,
                                                     const u16* __restrict__ Bt,
                                                     float* __restrict__ C,
                                                     int M, int N, int K) {
  __shared__ u16 sA[128 * 64];  // 16KB
  __shared__ u16 sB[64 * 64];   // 8KB
  const int tid = threadIdx.x;
  const int wave = tid >> 6, lane = tid & 63;
  const int quad = lane >> 4, l15 = lane & 15;
  const int m0 = blockIdx.x * 128, n0 = blockIdx.y * 64;
  const u16* aP = A + (size_t)m0 * K;
  const u16* bP = Bt + (size_t)n0 * K;
  const int sr = lane >> 3;
  const int sc = ((lane & 7) ^ ((lane >> 3) & 7)) * 8;
  const int sw = l15 & 7;
  const int wm = wave * 32;

  f32x4 acc[2][4];
  for (int i = 0; i < 2; i++)
    for (int j = 0; j < 4; j++)
      for (int r = 0; r < 4; r++) acc[i][j][r] = 0.0f;

  for (int k0 = 0; k0 < K; k0 += 64) {
    for (int is = 0; is < 4; is++)
      gl2lds16(aP + (size_t)(wm + is * 8 + sr) * K + k0 + sc, &sA[(wm + is * 8) * 64]);
    for (int is = 0; is < 2; is++)
      gl2lds16(bP + (size_t)(wave * 16 + is * 8 + sr) * K + k0 + sc, &sB[(wave * 16 + is * 8) * 64]);
    __syncthreads();
    for (int ks = 0; ks < 2; ks++) {
      bf16x8 afrag[2], bfrag[4];
      for (int i = 0; i < 2; i++)
        afrag[i] = *(const bf16x8*)&sA[(wm + i * 16 + l15) * 64 + ((ks * 4 + quad) ^ sw) * 8];
      for (int j = 0; j < 4; j++)
        bfrag[j] = *(const bf16x8*)&sB[(j * 16 + l15) * 64 + ((ks * 4 + quad) ^ sw) * 8];
      for (int i = 0; i < 2; i++)
        for (int j = 0; j < 4; j++)
          acc[i][j] = __builtin_amdgcn_mfma_f32_16x16x32_bf16(afrag[i], bfrag[j], acc[i][j], 0, 0, 0);
    }
    __syncthreads();
  }
  for (int i = 0; i < 2; i++)
    for (int j = 0; j < 4; j++) {
      int row = m0 + wm + i * 16 + quad * 4;
      int col = n0 + j * 16 + l15;
      for (int r = 0; r < 4; r++)
        C[(size_t)(row + r) * N + col] = acc[i][j][r];
    }
}

// ---------------- K-norm + deinterleave CKV -> K, V^T (coalesced) ----------------
__global__ __launch_bounds__(256) void knorm_deint(const u16* __restrict__ CKV,
                                                   const float* __restrict__ w,
                                                   u16* __restrict__ K,
                                                   u16* __restrict__ Vt) {
  __shared__ u16 vbuf[128][66];
  const int tid = threadIdx.x, wave = tid >> 6, lane = tid & 63;
  const int l0 = blockIdx.x * 64, kvh = blockIdx.y, b = blockIdx.z;
  for (int it = 0; it < 16; it++) {
    int ll = wave * 16 + it;
    int row = b * L_ + l0 + ll;
    const u16* src = CKV + (size_t)row * 1024 + kvh * 256;
    u32 p0 = *(const u32*)&src[lane * 2];
    u32 p1 = *(const u32*)&src[(lane + 64) * 2];
    float k0 = bf2f(p0 & 0xffff), v0 = bf2f(p0 >> 16);
    float k1 = bf2f(p1 & 0xffff), v1 = bf2f(p1 >> 16);
    float ss = k0 * k0 + k1 * k1;
    for (int off = 1; off < 64; off <<= 1) ss += __shfl_xor(ss, off);
    float sc = rsqrtf(ss * (1.0f / 128.0f) + EPS_);
    size_t kb = (((size_t)b * KVH_ + kvh) * L_ + l0 + ll) * D_;
    K[kb + lane] = f2bf(k0 * sc * w[lane]);
    K[kb + lane + 64] = f2bf(k1 * sc * w[lane + 64]);
    vbuf[lane][ll] = f2bf(v0);
    vbuf[lane + 64][ll] = f2bf(v1);
  }
  __syncthreads();
  for (int it = tid; it < 128 * 32; it += 256) {
    int d = it >> 5, cc = (it & 31) * 2;
    u32 pk = (u32)vbuf[d][cc] | ((u32)vbuf[d][cc + 1] << 16);
    *(u32*)&Vt[(((size_t)b * KVH_ + kvh) * D_ + d) * L_ + l0 + cc] = pk;
  }
}

// ---------------- flash attention (R3 structure: measured ~88us) ----------------
// 8 waves x 16 q-rows (512-thread block): 2 blocks/CU, 4 waves/SIMD.
// KV-tile 64 double-buffered, counted-vmcnt raw barriers, XOR-swizzle, setprio.
// Runs at ~89% of the ds_read_b128 throughput ceiling (1KB LDS per MFMA);
// more q-rows/wave would lower traffic but spills at this occupancy (R4).
__global__ __launch_bounds__(512, 4) void attn(const u16* __restrict__ XQ,
                                               const float* __restrict__ nw,
                                               const u16* __restrict__ K,
                                               const u16* __restrict__ Vt,
                                               u16* __restrict__ AO) {
  __shared__ u16 sk[2][4][64 * 32];   // [buf][d-chunk][l-row 64][32 d]  32KB
  __shared__ u16 sv[2][2][128 * 32];  // [buf][l-chunk][d-row 128][32 l] 32KB
  const int tid = threadIdx.x, wave = tid >> 6, lane = tid & 63;
  const int quad = lane >> 4, l15 = lane & 15;
  const int qt = blockIdx.x, h = blockIdx.y, b = blockIdx.z;
  const int kvh = h >> 2;
  const int s0 = qt * 128, wr0 = wave * 16;

  const u16* kbase = K + ((size_t)(b * KVH_ + kvh) * L_) * D_;
  const u16* vbase = Vt + ((size_t)(b * KVH_ + kvh) * D_) * L_;
  const int srow = lane >> 2;
  const int scol = ((lane & 3) ^ ((lane >> 3) & 3)) * 8;
  const int swq = (quad ^ ((l15 >> 1) & 3)) * 8;  // read-side XOR
  const int kch = wave >> 1, khalf = wave & 1;   // K: d-chunk, row-half
  const int vch = wave >> 2, vqtr = wave & 3;    // V: l-chunk, d-quarter

  auto stage = [&](int l0, int buf) {
    const u16* kb = kbase + (size_t)l0 * D_ + kch * 32;
    for (int is = 0; is < 2; is++) {
      int row = khalf * 32 + is * 16;
      gl2lds16(kb + (size_t)(row + srow) * D_ + scol, &sk[buf][kch][row * 32]);
    }
    const u16* vb = vbase + l0 + vch * 32;
    for (int is = 0; is < 2; is++) {
      int drow = vqtr * 32 + is * 16;
      gl2lds16(vb + (size_t)(drow + srow) * L_ + scol, &sv[buf][vch][drow * 32]);
    }
  };

  // ---- one-time: load 16 q-rows, fused RMSNorm (+SCALE*log2e), to A-frags ----
  bf16x8 qf[4];
  {
    const float cexp = 0.12753102331322172f;  // (1/sqrt(128)) * log2(e)
    const u16* qr = XQ + (size_t)(b * S_ + s0 + wr0 + l15) * HID_ + h * D_;
    float vals[4][8];
    float ss = 0.0f;
    for (int kc = 0; kc < 4; kc++) {
      uint4 u = *(const uint4*)&qr[kc * 32 + quad * 8];
      u32 uu[4] = {u.x, u.y, u.z, u.w};
      for (int e = 0; e < 4; e++) {
        float lo = bf2f(uu[e] & 0xffff), hi = bf2f(uu[e] >> 16);
        vals[kc][2 * e] = lo;
        vals[kc][2 * e + 1] = hi;
        ss += lo * lo + hi * hi;
      }
    }
    ss += __shfl_xor(ss, 16);
    ss += __shfl_xor(ss, 32);
    float scale = rsqrtf(ss * (1.0f / 128.0f) + EPS_) * cexp;
    for (int kc = 0; kc < 4; kc++) {
      float4 w0 = *(const float4*)&nw[kc * 32 + quad * 8];
      float4 w1 = *(const float4*)&nw[kc * 32 + quad * 8 + 4];
      union { u32x4v u; bf16x8 v; } q;
      q.u.x = pack_bf16(vals[kc][0] * scale * w0.x, vals[kc][1] * scale * w0.y);
      q.u.y = pack_bf16(vals[kc][2] * scale * w0.z, vals[kc][3] * scale * w0.w);
      q.u.z = pack_bf16(vals[kc][4] * scale * w1.x, vals[kc][5] * scale * w1.y);
      q.u.w = pack_bf16(vals[kc][6] * scale * w1.z, vals[kc][7] * scale * w1.w);
      qf[kc] = q.v;
    }
  }

  float psum = 0.0f;
  f32x4 o[8];
  for (int n = 0; n < 8; n++)
    for (int r = 0; r < 4; r++) o[n][r] = 0.0f;

  stage(0, 0);
  int cur = 0;
  const int NT = L_ / 64;  // 32
  for (int t = 0; t < NT; t++) {
    if (t + 1 < NT) {
      stage((t + 1) * 64, cur ^ 1);
      asm volatile("s_waitcnt vmcnt(4)\n\ts_barrier" ::: "memory");
    } else {
      asm volatile("s_waitcnt vmcnt(0)\n\ts_barrier" ::: "memory");
    }

    for (int cc = 0; cc < 2; cc++) {
      f32x4 sacc[2];
      for (int jj = 0; jj < 2; jj++)
        for (int r = 0; r < 4; r++) sacc[jj][r] = 0.0f;
      __builtin_amdgcn_s_setprio(1);
      for (int jj = 0; jj < 2; jj++) {
        int j = cc * 2 + jj;
        for (int kc = 0; kc < 4; kc++) {
          bf16x8 kf = *(const bf16x8*)&sk[cur][kc][(j * 16 + l15) * 32 + swq];
          sacc[jj] = __builtin_amdgcn_mfma_f32_16x16x32_bf16(kf, qf[kc], sacc[jj], 0, 0, 0);
        }
      }
      __builtin_amdgcn_s_setprio(0);
      union { u32x4v u; bf16x8 v; } pf;
      {
        float p0[4], p1[4];
        for (int r = 0; r < 4; r++) {
          p0[r] = fexp2(sacc[0][r]);
          p1[r] = fexp2(sacc[1][r]);
          psum += p0[r] + p1[r];
        }
        u32 xa = pack_bf16(p0[0], p0[1]), xb = pack_bf16(p0[2], p0[3]);
        u32 ya = pack_bf16(p1[0], p1[1]), yb = pack_bf16(p1[2], p1[3]);
        pf.u = ctoa(xa, xb, ya, yb, quad, l15);
      }
      __builtin_amdgcn_s_setprio(1);
      for (int n = 0; n < 8; n++) {
        bf16x8 vf = *(const bf16x8*)&sv[cur][cc][(n * 16 + l15) * 32 + swq];
        o[n] = __builtin_amdgcn_mfma_f32_16x16x32_bf16(pf.v, vf, o[n], 0, 0, 0);
      }
      __builtin_amdgcn_s_setprio(0);
    }
    asm volatile("s_barrier" ::: "memory");
    cur ^= 1;
  }

  // epilogue: reduce psum across quads (lane=q replicated), scale, store
  {
    float s = psum;
    s += __shfl_xor(s, 16);
    s += __shfl_xor(s, 32);
    float linv = 1.0f / s;
    float lr[4];
    for (int r = 0; r < 4; r++) lr[r] = __shfl(linv, quad * 4 + r);
    u16* ob = AO + (size_t)(b * S_ + s0 + wr0) * HID_ + h * D_;
    for (int n = 0; n < 8; n++)
      for (int r = 0; r < 4; r++)
        ob[(size_t)(quad * 4 + r) * HID_ + n * 16 + l15] = f2bf(o[n][r] * lr[r]);
  }
}

// ---------------- launch ----------------
extern "C" void kernel_launch(void* const* d_in, const int* in_sizes, int n_in,
                              void* d_out, int out_size, void* d_ws, size_t ws_size,
                              hipStream_t stream) {
  const float* x = (const float*)d_in[0];
  const float* c = (const float*)d_in[1];
  const float* wq = (const float*)d_in[2];
  const float* wkv = (const float*)d_in[3];
  const float* wo = (const float*)d_in[4];
  const float* nqw = (const float*)d_in[5];
  const float* nkw = (const float*)d_in[6];
  float* out = (float*)d_out;

  const int M = B_ * S_;  // 4096
  char* p = (char*)d_ws;
  auto alloc = [&](size_t bytes) {
    char* r = p;
    p += (bytes + 255) & ~(size_t)255;
    return r;
  };
  u16* xbf = (u16*)alloc((size_t)M * HID_ * 2);
  u16* cbf = (u16*)alloc((size_t)M * HID_ * 2);
  u16* wqT = (u16*)alloc((size_t)HID_ * HID_ * 2);
  u16* wkvT = (u16*)alloc((size_t)1024 * HID_ * 2);
  u16* woT = (u16*)alloc((size_t)HID_ * HID_ * 2);
  u16* XQ = (u16*)alloc((size_t)M * HID_ * 2);
  u16* CKV = (u16*)alloc((size_t)M * 1024 * 2);
  u16* Kb = (u16*)alloc((size_t)B_ * KVH_ * L_ * D_ * 2);
  u16* Vt = (u16*)alloc((size_t)B_ * KVH_ * D_ * L_ * 2);
  u16* AO = (u16*)alloc((size_t)M * HID_ * 2);

  const int n4 = M * HID_ / 4;  // 2097152
  prep<<<18944, 256, 0, stream>>>(x, xbf, c, cbf, wq, wqT, wkv, wkvT, wo, woT, n4);
  gemm_dual<<<dim3(32, 24), 256, 0, stream>>>(xbf, wqT, XQ, HID_,
                                              cbf, wkvT, CKV, 1024, HID_, 16);
  knorm_deint<<<dim3(32, 4, 2), 256, 0, stream>>>(CKV, nkw, Kb, Vt);
  attn<<<dim3(16, 16, 2), 512, 0, stream>>>(XQ, nqw, Kb, Vt, AO);
  gemm_out64<<<dim3(32, 32), 256, 0, stream>>>(AO, woT, out, M, HID_, HID_);
}